// Round 5
// baseline (127.646 us; speedup 1.0000x reference)
//
#include <hip/hip_runtime.h>
#include <hip/hip_bf16.h>
#include <math.h>

// B=4, T=128, S=512, D=512. Outputs: attn_h (4,128,512) then align (4,128,512), fp32.
// Pipeline (3 kernels):
//   1. fused_front: Ew=exp(2(inp@Wq^T+bq)), Eu=exp(2 ctx@Wc^T),
//      GT=(WL@ctx^T) bf16, Y0=inp@WR^T+bout   [all independent GEMMs]
//   2. align: Sraw[b,t,s] = V - 2*sum_d v/(1+Ew*Eu)   (== sum v*tanh(wq+uh))
//   3. gemm_att: row-softmax(Sraw) fused into staging; attn = P@GT^T + Y0;
//      bn==0 blocks write softmaxed P to d_out.

typedef __attribute__((ext_vector_type(8))) short short8;
typedef __attribute__((ext_vector_type(4))) float f32x4;
typedef unsigned short ushort_t;

static __device__ __forceinline__ unsigned short f2bf(float x) {
    union { __hip_bfloat16 h; unsigned short u; } c;
    c.h = __float2bfloat16(x);
    return c.u;
}
static __device__ __forceinline__ int bf2x(float lo, float hi) {
    return (int)(((unsigned)f2bf(hi) << 16) | (unsigned)f2bf(lo));
}

// Load 16 contiguous elements (fp32->cvt or bf16 direct) as 16 bf16 in 2 int4.
template<bool BF>
static __device__ __forceinline__ void load16(const void* base, size_t elemoff,
                                              int4& r0, int4& r1) {
    if (BF) {
        const int4* p = (const int4*)((const ushort_t*)base + elemoff);
        r0 = p[0]; r1 = p[1];
    } else {
        const float4* p = (const float4*)((const float*)base + elemoff);
        float4 a = p[0], b = p[1], c = p[2], d = p[3];
        r0.x = bf2x(a.x, a.y); r0.y = bf2x(a.z, a.w);
        r0.z = bf2x(b.x, b.y); r0.w = bf2x(b.z, b.w);
        r1.x = bf2x(c.x, c.y); r1.y = bf2x(c.z, c.w);
        r1.z = bf2x(d.x, d.y); r1.w = bf2x(d.z, d.w);
    }
}

// ---------------------------------------------------------------------------
// MFMA NT GEMM body: C[m,n] = sum_k A[m,k]*W[n,k] (+bias). 64x64 tile, BK=64,
// 256 thr = 4 waves (2x2 wave grid of 32x32), 2x2 MFMA 16x16x32 per 32-K.
// LDS rows padded to 72 bf16 -> <=2-way bank aliasing on b128 reads (free).
// EPI: 0 = fp32 (+bias); 1 = fp32 exp(2*(x+bias)); 2 = bf16.
// ---------------------------------------------------------------------------
template<bool A_BF, bool W_BF, int EPI>
static __device__ __forceinline__ void gemm_body(
    ushort_t* As, ushort_t* Ws,
    const void* A, const void* W, const float* bias,
    void* Cv, int K, int lda, int ldw, int ldc, int bm, int bn)
{
    const int tid = threadIdx.x;
    const int wave = tid >> 6, lane = tid & 63;
    const int mh = (wave & 1) * 32, nh = (wave >> 1) * 32;
    const int quad = lane >> 4, l16 = lane & 15;
    const int srow = tid >> 2, schunk = tid & 3;

    const size_t aoff = (size_t)(bm + srow) * lda + schunk * 16;
    const size_t woff = (size_t)(bn + srow) * ldw + schunk * 16;
    int4* AsW = (int4*)&As[srow * 72 + schunk * 16];
    int4* WsW = (int4*)&Ws[srow * 72 + schunk * 16];

    f32x4 acc00 = {0.f, 0.f, 0.f, 0.f}, acc01 = acc00, acc10 = acc00, acc11 = acc00;

    int4 a0r, a1r, w0r, w1r;
    load16<A_BF>(A, aoff, a0r, a1r);
    load16<W_BF>(W, woff, w0r, w1r);

    for (int k0 = 0; k0 < K; k0 += 64) {
        AsW[0] = a0r; AsW[1] = a1r;
        WsW[0] = w0r; WsW[1] = w1r;
        __syncthreads();
        if (k0 + 64 < K) {
            load16<A_BF>(A, aoff + k0 + 64, a0r, a1r);
            load16<W_BF>(W, woff + k0 + 64, w0r, w1r);
        }
        #pragma unroll
        for (int kk = 0; kk < 64; kk += 32) {
            short8 a0 = *(const short8*)&As[(mh + l16) * 72 + kk + quad * 8];
            short8 a1 = *(const short8*)&As[(mh + 16 + l16) * 72 + kk + quad * 8];
            short8 b0 = *(const short8*)&Ws[(nh + l16) * 72 + kk + quad * 8];
            short8 b1 = *(const short8*)&Ws[(nh + 16 + l16) * 72 + kk + quad * 8];
            acc00 = __builtin_amdgcn_mfma_f32_16x16x32_bf16(a0, b0, acc00, 0, 0, 0);
            acc01 = __builtin_amdgcn_mfma_f32_16x16x32_bf16(a0, b1, acc01, 0, 0, 0);
            acc10 = __builtin_amdgcn_mfma_f32_16x16x32_bf16(a1, b0, acc10, 0, 0, 0);
            acc11 = __builtin_amdgcn_mfma_f32_16x16x32_bf16(a1, b1, acc11, 0, 0, 0);
        }
        __syncthreads();
    }

    const int col0 = bn + nh + l16;
    const int col1 = col0 + 16;
    float bias0 = bias ? bias[col0] : 0.f;
    float bias1 = bias ? bias[col1] : 0.f;

    f32x4 accs[2][2] = {{acc00, acc01}, {acc10, acc11}};
    #pragma unroll
    for (int mt = 0; mt < 2; ++mt) {
        #pragma unroll
        for (int r = 0; r < 4; ++r) {
            int row = bm + mh + mt * 16 + quad * 4 + r;
            size_t rowoff = (size_t)row * ldc;
            float v0 = accs[mt][0][r] + bias0;
            float v1 = accs[mt][1][r] + bias1;
            if (EPI == 1) { v0 = __expf(2.f * v0); v1 = __expf(2.f * v1); }
            if (EPI == 2) {
                ushort_t* C = (ushort_t*)Cv;
                C[rowoff + col0] = f2bf(v0);
                C[rowoff + col1] = f2bf(v1);
            } else {
                float* C = (float*)Cv;
                C[rowoff + col0] = v0;
                C[rowoff + col1] = v1;
            }
        }
    }
}

// ---------------------------------------------------------------------------
// Fused front (640 GEMM blocks):
// [0,64)    Ew = exp(2*(inp@Wq^T + bq))          (512x512, K=512)
// [64,320)  Eu = exp(2*(ctx@Wc^T))               (2048x512, K=512)
// [320,576) GT[b][n,s] = sum_d WL[n,d]*ctx[b][s,d]  bf16  (4 x 512x512)
// [576,640) Y0 = inp@WR^T + bout                 (512x512, K=512)
// ---------------------------------------------------------------------------
__global__ __launch_bounds__(256) void fused_front(
    const float* __restrict__ inp, const float* __restrict__ ctx,
    const float* __restrict__ Wq, const float* __restrict__ bq,
    const float* __restrict__ Wc, const float* __restrict__ Wout,
    const float* __restrict__ bout,
    float* __restrict__ Ew, float* __restrict__ Eu, float* __restrict__ Y0,
    ushort_t* __restrict__ GT)
{
    __shared__ ushort_t As[64 * 72];
    __shared__ ushort_t Ws[64 * 72];
    const int bid = blockIdx.x;

    if (bid < 64) {
        gemm_body<false, false, 1>(As, Ws, inp, Wq, bq, Ew,
                                   512, 512, 512, 512, (bid & 7) * 64, (bid >> 3) * 64);
    } else if (bid < 320) {
        int i = bid - 64;
        gemm_body<false, false, 1>(As, Ws, ctx, Wc, nullptr, Eu,
                                   512, 512, 512, 512, (i & 31) * 64, (i >> 5) * 64);
    } else if (bid < 576) {
        int i = bid - 320;
        int b = i >> 6, j = i & 63;
        gemm_body<false, false, 2>(As, Ws, Wout, ctx + (size_t)b * 262144, nullptr,
                                   GT + (size_t)b * 262144,
                                   512, 1024, 512, 512, (j & 7) * 64, (j >> 3) * 64);
    } else {
        int i = bid - 576;
        gemm_body<false, false, 0>(As, Ws, inp, Wout + 512, bout, Y0,
                                   512, 512, 1024, 512, (i & 7) * 64, (i >> 3) * 64);
    }
}

// ---------------------------------------------------------------------------
// Sraw[b,t,s] = V - 2*sum_d v[d]/(1 + Ew[b,t,d]*Eu[b,s,d]),  V = sum_d v[d]
// Wave w: t = t0+2w..+1, s = s0..s0+7. Grid (64, 16, 4).
// ---------------------------------------------------------------------------
__global__ __launch_bounds__(256) void align_kernel(
    const float* __restrict__ Ew, const float* __restrict__ Eu,
    const float* __restrict__ v, float* __restrict__ out)
{
    const int lane = threadIdx.x & 63, wave = threadIdx.x >> 6;
    const int b = blockIdx.z;
    const int t0 = blockIdx.y * 8 + wave * 2;
    const int s0 = blockIdx.x * 8;

    const float* w0p = Ew + (((size_t)(b * 128 + t0)) << 9);
    const float* w1p = w0p + 512;
    const float* up  = Eu + (((size_t)(b * 512 + s0)) << 9);

    float acc0[8], acc1[8];
    #pragma unroll
    for (int j = 0; j < 8; ++j) { acc0[j] = 0.f; acc1[j] = 0.f; }
    float vsum = 0.f;

    for (int k0 = 0; k0 < 512; k0 += 64) {
        float vk = v[k0 + lane];
        vsum += vk;
        float w0 = w0p[k0 + lane];
        float w1 = w1p[k0 + lane];
        #pragma unroll
        for (int j = 0; j < 8; ++j) {
            float u = up[((size_t)j << 9) + k0 + lane];
            float d0 = fmaf(w0, u, 1.f);
            float d1 = fmaf(w1, u, 1.f);
            float r0 = __builtin_amdgcn_rcpf(d0);
            float r1 = __builtin_amdgcn_rcpf(d1);
            acc0[j] = fmaf(vk, r0, acc0[j]);
            acc1[j] = fmaf(vk, r1, acc1[j]);
        }
    }

    float V = vsum;
    #pragma unroll
    for (int off = 32; off; off >>= 1) V += __shfl_xor(V, off, 64);

    float r0 = 0.f, r1 = 0.f;
    #pragma unroll
    for (int j = 0; j < 8; ++j) {
        float a = acc0[j], c = acc1[j];
        #pragma unroll
        for (int off = 32; off; off >>= 1) {
            a += __shfl_xor(a, off, 64);
            c += __shfl_xor(c, off, 64);
        }
        if (lane == j) { r0 = fmaf(-2.f, a, V); r1 = fmaf(-2.f, c, V); }
    }
    if (lane < 8) {
        size_t o = (((size_t)(b * 128 + t0)) << 9) + s0 + lane;
        out[o] = r0;
        out[o + 512] = r1;
    }
}

// ---------------------------------------------------------------------------
// gemm_att: attn[b,t,n] = sum_s softmax(Sraw[b,t,:])[s] * GT[b][n,s] + Y0.
// Softmax fused: prepass computes per-row max/sum (4 staging threads per row,
// shuffle-reduced); staging applies exp(x-m)*rinv and converts to bf16.
// bn==0 blocks also write the softmaxed fp32 row to d_out (align_vectors).
// Grid (2, 8, 4) = 64 blocks.
// ---------------------------------------------------------------------------
__global__ __launch_bounds__(256) void gemm_att(
    const float* __restrict__ Sraw, const ushort_t* __restrict__ GT,
    const float* __restrict__ Y0, float* __restrict__ attn,
    float* __restrict__ alignv)
{
    __shared__ ushort_t As[64 * 72];
    __shared__ ushort_t Ws[64 * 72];
    const int tid = threadIdx.x;
    const int b = blockIdx.z;
    const int bm = blockIdx.x * 64;
    const int bn = blockIdx.y * 64;
    const int wave = tid >> 6, lane = tid & 63;
    const int mh = (wave & 1) * 32, nh = (wave >> 1) * 32;
    const int quad = lane >> 4, l16 = lane & 15;
    const int srow = tid >> 2, schunk = tid & 3;

    const float* Srow = Sraw + (((size_t)(b * 128 + bm + srow)) << 9);

    // --- softmax prepass: max & sum over this thread's quarter, 4-lane reduce
    const float4* qv = (const float4*)(Srow + schunk * 128);
    float mloc = -3.4e38f;
    #pragma unroll
    for (int i = 0; i < 32; ++i) {
        float4 x = qv[i];
        mloc = fmaxf(mloc, fmaxf(fmaxf(x.x, x.y), fmaxf(x.z, x.w)));
    }
    mloc = fmaxf(mloc, __shfl_xor(mloc, 1, 64));
    mloc = fmaxf(mloc, __shfl_xor(mloc, 2, 64));
    float ssum = 0.f;
    #pragma unroll
    for (int i = 0; i < 32; ++i) {
        float4 x = qv[i];
        ssum += __expf(x.x - mloc) + __expf(x.y - mloc)
              + __expf(x.z - mloc) + __expf(x.w - mloc);
    }
    ssum += __shfl_xor(ssum, 1, 64);
    ssum += __shfl_xor(ssum, 2, 64);
    const float rinv = __builtin_amdgcn_rcpf(ssum);

    const bool wr = (blockIdx.y == 0);
    float* arow = alignv + (((size_t)(b * 128 + bm + srow)) << 9);
    const ushort_t* GTb = GT + (size_t)b * 262144;
    const size_t woff = (size_t)(bn + srow) * 512 + schunk * 16;
    int4* AsW = (int4*)&As[srow * 72 + schunk * 16];
    int4* WsW = (int4*)&Ws[srow * 72 + schunk * 16];

    f32x4 acc00 = {0.f, 0.f, 0.f, 0.f}, acc01 = acc00, acc10 = acc00, acc11 = acc00;

    for (int k0 = 0; k0 < 512; k0 += 64) {
        const float4* ap = (const float4*)(Srow + k0 + schunk * 16);
        float4 x0 = ap[0], x1 = ap[1], x2 = ap[2], x3 = ap[3];
        float4 p0, p1, p2, p3;
        p0.x = __expf(x0.x - mloc) * rinv; p0.y = __expf(x0.y - mloc) * rinv;
        p0.z = __expf(x0.z - mloc) * rinv; p0.w = __expf(x0.w - mloc) * rinv;
        p1.x = __expf(x1.x - mloc) * rinv; p1.y = __expf(x1.y - mloc) * rinv;
        p1.z = __expf(x1.z - mloc) * rinv; p1.w = __expf(x1.w - mloc) * rinv;
        p2.x = __expf(x2.x - mloc) * rinv; p2.y = __expf(x2.y - mloc) * rinv;
        p2.z = __expf(x2.z - mloc) * rinv; p2.w = __expf(x2.w - mloc) * rinv;
        p3.x = __expf(x3.x - mloc) * rinv; p3.y = __expf(x3.y - mloc) * rinv;
        p3.z = __expf(x3.z - mloc) * rinv; p3.w = __expf(x3.w - mloc) * rinv;
        int4 w0r, w1r;
        load16<true>(GTb, woff + k0, w0r, w1r);
        if (wr) {
            float4* d = (float4*)(arow + k0 + schunk * 16);
            d[0] = p0; d[1] = p1; d[2] = p2; d[3] = p3;
        }
        int4 a0r, a1r;
        a0r.x = bf2x(p0.x, p0.y); a0r.y = bf2x(p0.z, p0.w);
        a0r.z = bf2x(p1.x, p1.y); a0r.w = bf2x(p1.z, p1.w);
        a1r.x = bf2x(p2.x, p2.y); a1r.y = bf2x(p2.z, p2.w);
        a1r.z = bf2x(p3.x, p3.y); a1r.w = bf2x(p3.z, p3.w);
        __syncthreads();
        AsW[0] = a0r; AsW[1] = a1r;
        WsW[0] = w0r; WsW[1] = w1r;
        __syncthreads();
        #pragma unroll
        for (int kk = 0; kk < 64; kk += 32) {
            short8 a0 = *(const short8*)&As[(mh + l16) * 72 + kk + quad * 8];
            short8 a1 = *(const short8*)&As[(mh + 16 + l16) * 72 + kk + quad * 8];
            short8 b0 = *(const short8*)&Ws[(nh + l16) * 72 + kk + quad * 8];
            short8 b1 = *(const short8*)&Ws[(nh + 16 + l16) * 72 + kk + quad * 8];
            acc00 = __builtin_amdgcn_mfma_f32_16x16x32_bf16(a0, b0, acc00, 0, 0, 0);
            acc01 = __builtin_amdgcn_mfma_f32_16x16x32_bf16(a0, b1, acc01, 0, 0, 0);
            acc10 = __builtin_amdgcn_mfma_f32_16x16x32_bf16(a1, b0, acc10, 0, 0, 0);
            acc11 = __builtin_amdgcn_mfma_f32_16x16x32_bf16(a1, b1, acc11, 0, 0, 0);
        }
    }

    const int col0 = bn + nh + l16;
    const int col1 = col0 + 16;
    f32x4 accs[2][2] = {{acc00, acc01}, {acc10, acc11}};
    #pragma unroll
    for (int mt = 0; mt < 2; ++mt) {
        #pragma unroll
        for (int r = 0; r < 4; ++r) {
            size_t rowoff = (size_t)(b * 128 + bm + mh + mt * 16 + quad * 4 + r) << 9;
            attn[rowoff + col0] = accs[mt][0][r] + Y0[rowoff + col0];
            attn[rowoff + col1] = accs[mt][1][r] + Y0[rowoff + col1];
        }
    }
}

// ---------------------------------------------------------------------------
extern "C" void kernel_launch(void* const* d_in, const int* in_sizes, int n_in,
                              void* d_out, int out_size, void* d_ws, size_t ws_size,
                              hipStream_t stream)
{
    const float* inp  = (const float*)d_in[0];   // (4,128,512)
    const float* ctx  = (const float*)d_in[1];   // (4,512,512)
    const float* Wq   = (const float*)d_in[2];   // (512,512)
    const float* bq   = (const float*)d_in[3];   // (512)
    const float* Wc   = (const float*)d_in[4];   // (512,512)
    const float* v    = (const float*)d_in[5];   // (512)
    const float* Wout = (const float*)d_in[6];   // (512,1024)
    const float* bout = (const float*)d_in[7];   // (512)

    float* out   = (float*)d_out;
    float* attn  = out;              // 262144 floats
    float* align = out + 262144;     // 262144 floats

    float* ws = (float*)d_ws;
    float* Ew   = ws;                          // 262144 f
    float* Eu   = ws + 262144;                 // 1048576 f
    float* Y0   = ws + 1310720;                // 262144 f
    float* Sraw = ws + 1572864;                // 262144 f
    ushort_t* GT = (ushort_t*)(ws + 1835008);  // 4 x 262144 u16

    fused_front<<<dim3(640), 256, 0, stream>>>(inp, ctx, Wq, bq, Wc, Wout, bout,
                                               Ew, Eu, Y0, GT);
    align_kernel<<<dim3(64, 16, 4), 256, 0, stream>>>(Ew, Eu, v, Sraw);
    gemm_att<<<dim3(2, 8, 4), 256, 0, stream>>>(Sraw, GT, Y0, attn, align);
}